// Round 2
// baseline (1097.165 us; speedup 1.0000x reference)
//
#include <hip/hip_runtime.h>
#include <math.h>

// SwitchGate: T=16384, D=4096, E=64, CAP_RATE=2.4.
// capacity = ceil(2.4*16384) = 39322 > T  =>  pruning never triggers:
//   pruned_idx == top1_idx, n_valid == T.
// loss = (E / T^2) * sum_e count[e] * score_sum[e]
//
// d_out (float32): [0,T) pruned_idx (as float) | [T,2T) top1_score | [2T] loss
//
// Strategy: lane == expert (E == wavefront size 64).
//  - Each wave owns 8 tokens; lane e accumulates logit[tok][e] in regs.
//  - inp rows are wave-uniform addresses -> scalar/broadcast loads (no LDS).
//  - W staged per 64-k chunk in LDS, layout [k4][expert][4] so each lane
//    reads its expert's 4 k-values with one aligned ds_read_b128,
//    each bank serving exactly 8 words -> conflict-free.
//  - LDS bytes/FMA = 0.5 (vs 3.0 in round 1, which was LDS-throughput-bound).

#define T_TOK 16384
#define D_DIM 4096
#define E_EXP 64
#define BK 64

// ---------------------------------------------------------------- zero ws
__global__ void zero_ws_kernel(float* __restrict__ wsf, int* __restrict__ wsc) {
    int t = threadIdx.x;
    if (t < 64) wsf[t] = 0.0f;
    else if (t < 128) wsc[t - 64] = 0;
}

// ---------------------------------------------------------------- main
// 512 blocks x 256 threads (4 waves). Block = 32 tokens, wave = 8 tokens.
__global__ __launch_bounds__(256) void gate_main_kernel(
    const float* __restrict__ inp,   // [T, D]
    const float* __restrict__ W,     // [E, D]
    const float* __restrict__ b,     // [E]
    float* __restrict__ out,         // [2T+1]
    float* __restrict__ g_sum,       // [64]
    int*   __restrict__ g_cnt)       // [64]
{
    __shared__ float W_s[BK / 4][E_EXP][4];   // 16 KB, transposed k-major tiles

    const int tid  = threadIdx.x;
    const int lane = tid & 63;        // expert id
    const int wave = tid >> 6;        // 0..3
    const int tok_base = blockIdx.x * 32 + wave * 8;

    // staging map: thread i -> W row r = i>>2, 16 floats at col 16*(i&3)
    const int s_r = tid >> 2;
    const int s_c = tid & 3;
    const float* w_ptr = W + (size_t)s_r * D_DIM + 16 * s_c;

    // prefetch chunk 0 into registers
    float4 stage[4];
#pragma unroll
    for (int q = 0; q < 4; ++q)
        stage[q] = ((const float4*)w_ptr)[q];

    float acc[8];
#pragma unroll
    for (int t = 0; t < 8; ++t) acc[t] = 0.0f;

    // wave-uniform token row pointers (readfirstlane -> provably uniform)
    const float* a_row[8];
#pragma unroll
    for (int t = 0; t < 8; ++t) {
        const int tok = __builtin_amdgcn_readfirstlane(tok_base + t);
        a_row[t] = inp + (size_t)tok * D_DIM;
    }

    for (int kc = 0; kc < D_DIM; kc += BK) {
        __syncthreads();                       // consumers of prev chunk done
#pragma unroll
        for (int q = 0; q < 4; ++q)
            *(float4*)&W_s[4 * s_c + q][s_r][0] = stage[q];
        if (kc + BK < D_DIM) {                 // prefetch next chunk (in flight
            const float* p = w_ptr + kc + BK;  //  during this chunk's compute)
#pragma unroll
            for (int q = 0; q < 4; ++q)
                stage[q] = ((const float4*)p)[q];
        }
        __syncthreads();                       // W_s ready

#pragma unroll
        for (int kk4 = 0; kk4 < BK / 4; ++kk4) {
            const float4 w4 = *(const float4*)&W_s[kk4][lane][0];
#pragma unroll
            for (int t = 0; t < 8; ++t) {
                const float4 a4 = *(const float4*)(a_row[t] + kc + 4 * kk4);
                acc[t] += a4.x * w4.x;
                acc[t] += a4.y * w4.y;
                acc[t] += a4.z * w4.z;
                acc[t] += a4.w * w4.w;
            }
        }
    }

    // ---- epilogue: in-wave softmax/top1, private per-expert accumulation ----
    const float bias = b[lane];
    float sum_e = 0.0f;
    int   cnt_e = 0;

#pragma unroll
    for (int t = 0; t < 8; ++t) {
        const float l = acc[t] + bias;

        float mv = l; int mi = lane;
#pragma unroll
        for (int off = 1; off < 64; off <<= 1) {
            const float ov = __shfl_xor(mv, off, 64);
            const int   oi = __shfl_xor(mi, off, 64);
            if (ov > mv || (ov == mv && oi < mi)) { mv = ov; mi = oi; }
        }

        const float ex = __expf(l - mv);
        float s = ex;
#pragma unroll
        for (int off = 1; off < 64; off <<= 1) s += __shfl_xor(s, off, 64);
        const float inv = 1.0f / s;            // top-1 score

        if (lane == 0) {
            out[tok_base + t]         = (float)mi;  // never capacity-pruned
            out[T_TOK + tok_base + t] = inv;
        }
        sum_e += ex * inv;                     // softmax prob of expert `lane`
        cnt_e += (lane == mi) ? 1 : 0;
    }

    atomicAdd(&g_sum[lane], sum_e);
    atomicAdd(&g_cnt[lane], cnt_e);
}

// ---------------------------------------------------------------- loss
__global__ void gate_loss_kernel(const float* __restrict__ g_sum,
                                 const int* __restrict__ g_cnt,
                                 float* __restrict__ out) {
    const int e = threadIdx.x;   // 64 threads = 1 wave
    float v = g_sum[e] * (float)g_cnt[e];
#pragma unroll
    for (int off = 32; off > 0; off >>= 1) v += __shfl_xor(v, off, 64);
    if (e == 0)
        out[2 * T_TOK] = v * (float)E_EXP / ((float)T_TOK * (float)T_TOK);
}

// ---------------------------------------------------------------- launch
extern "C" void kernel_launch(void* const* d_in, const int* in_sizes, int n_in,
                              void* d_out, int out_size, void* d_ws, size_t ws_size,
                              hipStream_t stream) {
    const float* inp = (const float*)d_in[0];
    const float* W   = (const float*)d_in[1];
    const float* b   = (const float*)d_in[2];
    float* out = (float*)d_out;

    float* g_sum = (float*)d_ws;           // 64 floats
    int*   g_cnt = (int*)(g_sum + 64);     // 64 ints

    zero_ws_kernel<<<1, 128, 0, stream>>>(g_sum, g_cnt);
    gate_main_kernel<<<T_TOK / 32, 256, 0, stream>>>(inp, W, b, out, g_sum, g_cnt);
    gate_loss_kernel<<<1, 64, 0, stream>>>(g_sum, g_cnt, out);
}

// Round 4
// 508.786 us; speedup vs baseline: 2.1564x; 2.1564x over previous
//
#include <hip/hip_runtime.h>
#include <math.h>

// SwitchGate: T=16384, D=4096, E=64, CAP_RATE=2.4.
// capacity = ceil(2.4*16384) = 39322 > T  =>  pruning never triggers:
//   pruned_idx == top1_idx, n_valid == T.
// loss = (E / T^2) * sum_e count[e] * score_sum[e]
//
// d_out (float32): [0,T) pruned_idx (as float) | [T,2T) top1_score | [2T] loss
//
// Round-4 design: lane = token, W rows through the SCALAR pipe (no asm).
//  - Prologue transposes W -> WT[4096][64] (1 MB, d_ws; L2-resident).
//  - Main: 256 blocks x 512 thr (8 waves). Wave w owns k in [512w, 512w+512),
//    lanes = 64 tokens. The WT row pointer is wave-uniform by construction
//    (readfirstlane), so the compiler's uniformity analysis turns the row
//    loads into s_load_dwordx16 -> W lives in SGPRs, and the inner loop is
//    64x v_fmac_f32 v_acc, s_w, v_a : ONE instruction per FMA, zero LDS.
//    (Round-2 counters proved the compiler scalarizes uniform loads:
//     SGPR_Count=112. Round-3's inline-asm variant failed regalloc.)
//  - Split-K partials combined via LDS ds_add_f32 on a 65-padded tile
//    (banks (lane+e)%32 -> conflict-free), softmax/top1 in-block.

#define T_TOK 16384
#define D_DIM 4096
#define E_EXP 64
#define KSPLIT 8
#define KPW (D_DIM / KSPLIT)   // 512 k per wave

typedef float v16f __attribute__((ext_vector_type(16)));

// ---------------------------------------------------------------- zero ws
__global__ void zero_ws_kernel(float* __restrict__ wsf, int* __restrict__ wsc) {
    int t = threadIdx.x;
    if (t < 64) wsf[t] = 0.0f;
    else if (t < 128) wsc[t - 64] = 0;
}

// ---------------------------------------------------------------- W -> WT
__global__ __launch_bounds__(256) void transpose_w_kernel(
    const float* __restrict__ W, float* __restrict__ WT) {
    const int gid = blockIdx.x * 256 + threadIdx.x;  // 0..262143
    const int k = gid >> 6;
    const int e = gid & 63;
    WT[gid] = W[(size_t)e * D_DIM + k];
}

// ---------------------------------------------------------------- main
__global__ __launch_bounds__(512) void gate_main_kernel(
    const float* __restrict__ inp,   // [T, D]
    const float* __restrict__ WT,    // [D, E] transposed weights
    const float* __restrict__ b,     // [E]
    float* __restrict__ out,         // [2T+1]
    float* __restrict__ g_sum,       // [64]
    int*   __restrict__ g_cnt)       // [64]
{
    __shared__ float L[64][65];      // logits [token_local][expert], padded
    __shared__ float bs[64];
    __shared__ int   bc[64];

    const int tid  = threadIdx.x;
    const int lane = tid & 63;       // token (main loop), expert (epilogue)
    const int wid  = tid >> 6;       // 0..7, k-split id
    const int tok  = blockIdx.x * 64 + lane;
    // wave-uniform by construction -> enables SMEM selection for W loads
    const int kb0  = __builtin_amdgcn_readfirstlane(wid * KPW);

    float* Lf = &L[0][0];
    for (int i = tid; i < 64 * 65; i += 512) Lf[i] = 0.0f;
    if (tid < 64) { bs[tid] = 0.0f; bc[tid] = 0; }
    __syncthreads();

    float acc[E_EXP];
#pragma unroll
    for (int e = 0; e < E_EXP; ++e) acc[e] = 0.0f;

    const float* a_ptr   = inp + (size_t)tok * D_DIM + kb0;   // per-lane
    const v16f*  wt_base = (const v16f*)(WT + (size_t)kb0 * E_EXP); // uniform

    for (int kb = 0; kb < KPW; kb += 8) {
        const float4 A0 = *(const float4*)(a_ptr + kb);
        const float4 A1 = *(const float4*)(a_ptr + kb + 4);
        const float av[8] = {A0.x, A0.y, A0.z, A0.w, A1.x, A1.y, A1.z, A1.w};
#pragma unroll
        for (int kk = 0; kk < 8; ++kk) {
            const v16f* wp = wt_base + (size_t)(kb + kk) * 4;  // 64 floats/row
            const v16f w0 = wp[0];
            const v16f w1 = wp[1];
            const v16f w2 = wp[2];
            const v16f w3 = wp[3];
            const float a = av[kk];
#pragma unroll
            for (int j = 0; j < 16; ++j) {
                acc[j]      += a * w0[j];
                acc[j + 16] += a * w1[j];
                acc[j + 32] += a * w2[j];
                acc[j + 48] += a * w3[j];
            }
        }
    }

    // combine split-K partials; banks (lane*65+e)%32 = (lane+e)%32: conflict-free
#pragma unroll
    for (int e = 0; e < E_EXP; ++e)
        atomicAdd(&L[lane][e], acc[e]);
    __syncthreads();

    // ---- epilogue: wave wid handles tokens 8*wid..8*wid+7; lane = expert ----
    const float bias = b[lane];
    float priv_sum = 0.0f;
    int   priv_cnt = 0;
#pragma unroll
    for (int t = 0; t < 8; ++t) {
        const int tl = 8 * wid + t;
        const float l = L[tl][lane] + bias;

        float mv = l; int mi = lane;   // ties -> lowest index (lax.top_k)
#pragma unroll
        for (int off = 1; off < 64; off <<= 1) {
            const float ov = __shfl_xor(mv, off, 64);
            const int   oi = __shfl_xor(mi, off, 64);
            if (ov > mv || (ov == mv && oi < mi)) { mv = ov; mi = oi; }
        }

        const float ex = __expf(l - mv);
        float s = ex;
#pragma unroll
        for (int off = 1; off < 64; off <<= 1) s += __shfl_xor(s, off, 64);
        const float inv = 1.0f / s;    // top-1 score

        if (lane == 0) {
            const int gt = blockIdx.x * 64 + tl;
            out[gt]         = (float)mi;   // never capacity-pruned
            out[T_TOK + gt] = inv;
        }
        priv_sum += ex * inv;              // softmax prob of expert `lane`
        priv_cnt += (mi == lane) ? 1 : 0;
    }

    atomicAdd(&bs[lane], priv_sum);
    atomicAdd(&bc[lane], priv_cnt);
    __syncthreads();
    if (tid < 64) {
        atomicAdd(&g_sum[tid], bs[tid]);
        atomicAdd(&g_cnt[tid], bc[tid]);
    }
}

// ---------------------------------------------------------------- loss
__global__ void gate_loss_kernel(const float* __restrict__ g_sum,
                                 const int* __restrict__ g_cnt,
                                 float* __restrict__ out) {
    const int e = threadIdx.x;   // 64 threads = 1 wave
    float v = g_sum[e] * (float)g_cnt[e];
#pragma unroll
    for (int off = 32; off > 0; off >>= 1) v += __shfl_xor(v, off, 64);
    if (e == 0)
        out[2 * T_TOK] = v * (float)E_EXP / ((float)T_TOK * (float)T_TOK);
}

// ---------------------------------------------------------------- launch
extern "C" void kernel_launch(void* const* d_in, const int* in_sizes, int n_in,
                              void* d_out, int out_size, void* d_ws, size_t ws_size,
                              hipStream_t stream) {
    const float* inp = (const float*)d_in[0];
    const float* W   = (const float*)d_in[1];
    const float* b   = (const float*)d_in[2];
    float* out = (float*)d_out;

    float* WT    = (float*)d_ws;                         // 1 MB transposed W
    float* g_sum = (float*)((char*)d_ws + (1 << 20));    // 64 floats
    int*   g_cnt = (int*)(g_sum + 64);                   // 64 ints

    zero_ws_kernel<<<1, 128, 0, stream>>>(g_sum, g_cnt);
    transpose_w_kernel<<<(D_DIM * E_EXP) / 256, 256, 0, stream>>>(W, WT);
    gate_main_kernel<<<T_TOK / 64, 512, 0, stream>>>(inp, WT, b, out, g_sum, g_cnt);
    gate_loss_kernel<<<1, 64, 0, stream>>>(g_sum, g_cnt, out);
}